// Round 5
// baseline (804.085 us; speedup 1.0000x reference)
//
#include <hip/hip_runtime.h>
#include <hip/hip_bf16.h>

typedef unsigned short u16;
typedef __bf16 bf16x8 __attribute__((ext_vector_type(8)));
typedef float f32x4 __attribute__((ext_vector_type(4)));

#define B_IMG 128
#define NOBJ  36
#define NNODE (B_IMG * NOBJ)

__device__ __forceinline__ float b2f(u16 u) {
    union { unsigned int i; float f; } v; v.i = ((unsigned int)u) << 16; return v.f;
}
__device__ __forceinline__ u16 f2b(float f) {
    union { float f; unsigned int i; } v; v.f = f;
    unsigned int u = v.i;
    return (u16)((u + 0x7fffu + ((u >> 16) & 1u)) >> 16);   // RNE
}

// ---------------------------------------------------------------------------
// Merged activation convert: blocks [0,9216) pack of (fp32->bf16, x4/thread);
// blocks [9216,10496) pad-convert qe [128,2400] -> [128,2560] (zero cols>=2400).
// ---------------------------------------------------------------------------
__global__ __launch_bounds__(256)
void conv_all(const float* __restrict__ of, u16* __restrict__ of_c,
              const float* __restrict__ qe, u16* __restrict__ qe_c)
{
    const int bid = blockIdx.x;
    if (bid < 9216) {
        const int i = bid * 256 + threadIdx.x;   // < 4608*2048/4 exactly
        const float4 f = ((const float4*)of)[i];
        ushort4 o; o.x = f2b(f.x); o.y = f2b(f.y); o.z = f2b(f.z); o.w = f2b(f.w);
        ((ushort4*)of_c)[i] = o;
    } else {
        const int i = (bid - 9216) * 256 + threadIdx.x;  // < 128*2560 exactly
        const int r = i / 2560, c = i - r * 2560;
        qe_c[i] = (c < 2400) ? f2b(qe[r * 2400 + c]) : (u16)0;
    }
}

// ---------------------------------------------------------------------------
// Generic fused convert+transpose for TWO matrices in one launch.
// src [Rs, C] fp32 -> dst [C, Rd] bf16, rows k in [Rs, Rd) zero-filled.
// Tiles per matrix: (C/32) * (Rd/32); matrix 0 owns tiles [0, nt0).
// ---------------------------------------------------------------------------
__global__ __launch_bounds__(256)
void transpose_cvt2(const float* __restrict__ s0, u16* __restrict__ d0,
                    int Rs0, int Rd0, int C0, int nt0,
                    const float* __restrict__ s1, u16* __restrict__ d1,
                    int Rs1, int Rd1, int C1)
{
    __shared__ u16 tile[32][33];
    int tb = blockIdx.x;
    const float* src; u16* dst; int Rs, Rd, C;
    if (tb < nt0) { src = s0; dst = d0; Rs = Rs0; Rd = Rd0; C = C0; }
    else { tb -= nt0; src = s1; dst = d1; Rs = Rs1; Rd = Rd1; C = C1; }
    const int ntx = C >> 5;
    const int ty = tb / ntx, tx = tb - ty * ntx;
    const int bx = tx * 32, by = ty * 32;
    const int lx = threadIdx.x & 31, ly = threadIdx.x >> 5;   // 32x8
    #pragma unroll
    for (int i = ly; i < 32; i += 8) {
        const int k = by + i;
        tile[i][lx] = (k < Rs) ? f2b(src[(size_t)k * C + bx + lx]) : (u16)0;
    }
    __syncthreads();
    #pragma unroll
    for (int i = ly; i < 32; i += 8) dst[(size_t)(bx + i) * Rd + by + lx] = tile[lx][i];
}

// ---------------------------------------------------------------------------
// TN MFMA GEMM: C[M,N] = A[M,K] * Bt[N,K]^T   (bf16 in, fp32 acc)
// 128x128 tile, BK=32, 4 waves 2x2, per iter 4x4 16x16x32 MFMA.
// A-DIRECT: A fragments stream global->VGPR (per-lane 16B loads, 64B/row
// transactions, L2-served; no block-level A reuse needed — N/128 blocks
// re-read A panels through L2).  Register double-buffer a0/a1 with static
// indices (manual unroll-2; all call sites have even nIter).
// LDS carries ONLY B: 2 stages x 8 KB = 16 KB -> 4 blocks/CU, and per-iter
// LDS traffic halves vs A+B staging (the old ~3.5:1 LDS:MFMA pipe ratio).
// EPI: 1 = splitK fp32 partial, 2 = +bias then *qmul -> bf16, 0 = bf16.
// ---------------------------------------------------------------------------
template<int EPI>
__global__ __launch_bounds__(256, 4)
void gemm_tn(const u16* __restrict__ A, const u16* __restrict__ Bt,
             int M, int N, int K, int kLen,
             float* __restrict__ Cf, u16* __restrict__ Cb,
             const float* __restrict__ bias, const float* __restrict__ qmul)
{
    __shared__ __align__(16) u16 lds[2 * 4096];   // 16 KB (B only)

    const int t    = threadIdx.x;
    const int lane = t & 63;
    const int wave = t >> 6;
    const int wr = wave >> 1, wc = wave & 1;
    const int quad = lane >> 4, l16 = lane & 15;
    const int rowBase = blockIdx.y * 128;
    const int colBase = blockIdx.x * 128;
    const int k0 = blockIdx.z * kLen;

    // B staging: wave w owns rows [w*32, w*32+32); 2 DMA chunks of 16 rows.
    const u16* gB0 = Bt + (size_t)(colBase + wave * 32 + (lane >> 2)) * K + k0 + (lane & 3) * 8;
    const u16* gB1 = gB0 + 16 * (size_t)K;
    const int ro = wave * 1024;   // 32 rows * 32 u16

    // A direct-to-reg base: frag r = row (wr*64 + r*16 + l16), cols quad*8..+8
    const u16* gA = A + (size_t)(rowBase + wr * 64 + l16) * K + k0 + quad * 8;
    const size_t aRow16 = (size_t)16 * K;

    int bfr[4];
    #pragma unroll
    for (int c = 0; c < 4; c++) bfr[c] = (wc * 64 + c * 16 + l16) * 32 + quad * 8;

    f32x4 acc[4][4];
    #pragma unroll
    for (int r = 0; r < 4; r++)
        #pragma unroll
        for (int c = 0; c < 4; c++)
            acc[r][c] = (f32x4){0.f, 0.f, 0.f, 0.f};

    auto gld = [](const u16* g, u16* s) {
        __builtin_amdgcn_global_load_lds(
            (const __attribute__((address_space(1))) void*)g,
            (__attribute__((address_space(3))) void*)s, 16, 0, 0);
    };
    auto dmaB = [&](int it, int st) {
        const int kk = it * 32;
        const int bo = st * 4096;
        gld(gB0 + kk, &lds[bo + ro]);
        gld(gB1 + kk, &lds[bo + ro + 512]);
    };
    auto loadA = [&](bf16x8* d, int it) {
        const u16* p = gA + it * 32;
        #pragma unroll
        for (int r = 0; r < 4; r++) d[r] = *(const bf16x8*)(p + (size_t)r * aRow16);
    };
    auto compute = [&](int st, const bf16x8* av) {
        const int bo = st * 4096;
        bf16x8 bv[4];
        #pragma unroll
        for (int c = 0; c < 4; c++) bv[c] = *(const bf16x8*)&lds[bo + bfr[c]];
        #pragma unroll
        for (int r = 0; r < 4; r++)
            #pragma unroll
            for (int c = 0; c < 4; c++)
                acc[r][c] = __builtin_amdgcn_mfma_f32_16x16x32_bf16(av[r], bv[c], acc[r][c], 0, 0, 0);
    };

    const int nIter = kLen >> 5;   // even at all call sites (16/32/64)
    bf16x8 a0[4], a1[4];
    dmaB(0, 0);
    loadA(a0, 0);
    for (int it = 0; it < nIter; it += 2) {
        asm volatile("s_waitcnt vmcnt(0)\n\ts_barrier" ::: "memory");
        if (it + 1 < nIter) { dmaB(it + 1, 1); loadA(a1, it + 1); }
        compute(0, a0);
        asm volatile("s_waitcnt vmcnt(0)\n\ts_barrier" ::: "memory");
        if (it + 2 < nIter) { dmaB(it + 2, 0); loadA(a0, it + 2); }
        compute(1, a1);
    }

    // epilogue: D row = quad*4+reg, col = l16
    #pragma unroll
    for (int r = 0; r < 4; r++) {
        const int mBase = rowBase + wr * 64 + r * 16 + quad * 4;
        #pragma unroll
        for (int c = 0; c < 4; c++) {
            const int n = colBase + wc * 64 + c * 16 + l16;
            #pragma unroll
            for (int e = 0; e < 4; e++) {
                const int m = mBase + e;
                float v = acc[r][c][e];
                if (EPI == 1) {
                    Cf[((size_t)blockIdx.z * M + m) * N + n] = v;
                } else if (EPI == 2) {
                    v += bias[n];
                    v *= qmul[(size_t)(m / NOBJ) * N + n];
                    Cb[(size_t)m * N + n] = f2b(v);
                } else {
                    Cb[(size_t)m * N + n] = f2b(v);
                }
            }
        }
    }
}

// ---------------------------------------------------------------------------
__global__ __launch_bounds__(256)
void qcombine(const float* __restrict__ p, const float* __restrict__ bias,
              float* __restrict__ q, int MN, int S)
{
    const int i = blockIdx.x * 256 + threadIdx.x;
    float s = 0.f;
    for (int z = 0; z < S; z++) s += p[(size_t)z * MN + i];
    q[i] = s + bias[i & 2047];
}

// ---------------------------------------------------------------------------
// Fused attention per (image, head) — layers 1/2 (measured-best structure).
// MODE 1: relu(agg+b) -> g (bf16);  MODE 2: relu(agg+b)+resid -> g
// ---------------------------------------------------------------------------
template<int H, int C, int MODE>
__global__ __launch_bounds__(256)
void attn_kernel(const u16* __restrict__ h, const float* __restrict__ a_src,
                 const float* __restrict__ a_dst, const float* __restrict__ bias,
                 const u16* __restrict__ resid, u16* __restrict__ outb)
{
    __shared__ __align__(16) u16 hl[36 * C];
    __shared__ float alpha[36 * 36];
    __shared__ float asl[36], adl[36];
    __shared__ float psum[36][8][2];
    const int b = blockIdx.y, hd = blockIdx.x;
    const int t = threadIdx.x;
    const int nb = b * NOBJ;
    constexpr int CH = C / 8;
    for (int e = t; e < 36 * CH; e += 256) {
        const int row = e / CH, col = (e - row * CH) * 8;
        *(uint4*)&hl[row * C + col] = *(const uint4*)&h[(size_t)(nb + row) * (H * C) + hd * C + col];
    }
    __syncthreads();
    constexpr int SEG = C / 8;
    for (int e = t; e < 36 * 8; e += 256) {
        const int n = e >> 3, sg = e & 7;
        const u16*   hp = &hl[n * C + sg * SEG];
        const float* as = a_src + hd * C + sg * SEG;
        const float* ad = a_dst + hd * C + sg * SEG;
        float s1 = 0.f, s2 = 0.f;
        #pragma unroll 8
        for (int i = 0; i < SEG; i++) {
            const float hv = b2f(hp[i]);
            s1 += hv * as[i]; s2 += hv * ad[i];
        }
        psum[n][sg][0] = s1; psum[n][sg][1] = s2;
    }
    __syncthreads();
    if (t < 36) {
        float s1 = 0.f, s2 = 0.f;
        #pragma unroll
        for (int sg = 0; sg < 8; sg++) { s1 += psum[t][sg][0]; s2 += psum[t][sg][1]; }
        asl[t] = s1; adl[t] = s2;
    }
    __syncthreads();
    if (t < 36) {
        const float ad = adl[t];
        float mx = -1e30f;
        for (int s = 0; s < 36; s++) {
            float v = asl[s] + ad; v = (v > 0.f) ? v : 0.2f * v;
            alpha[t * 36 + s] = v; mx = fmaxf(mx, v);
        }
        float sum = 0.f;
        for (int s = 0; s < 36; s++) { const float ex = expf(alpha[t * 36 + s] - mx); alpha[t * 36 + s] = ex; sum += ex; }
        const float inv = 1.f / (sum + 1e-16f);
        for (int s = 0; s < 36; s++) alpha[t * 36 + s] *= inv;
    }
    __syncthreads();
    constexpr int NC4 = C / 4;
    for (int e = t; e < 36 * NC4; e += 256) {
        const int d = e / NC4, c4 = (e - d * NC4) * 4;
        float a0 = 0, a1 = 0, a2 = 0, a3 = 0;
        for (int s = 0; s < 36; s++) {
            const float al = alpha[d * 36 + s];
            const ushort4 hv = *(const ushort4*)&hl[s * C + c4];
            a0 += al * b2f(hv.x); a1 += al * b2f(hv.y); a2 += al * b2f(hv.z); a3 += al * b2f(hv.w);
        }
        const int n = nb + d;
        const size_t base = (size_t)n * (H * C) + hd * C + c4;
        const int bb = hd * C + c4;
        float v0 = a0 + bias[bb + 0];
        float v1 = a1 + bias[bb + 1];
        float v2 = a2 + bias[bb + 2];
        float v3 = a3 + bias[bb + 3];
        v0 = v0 > 0.f ? v0 : 0.f; v1 = v1 > 0.f ? v1 : 0.f;
        v2 = v2 > 0.f ? v2 : 0.f; v3 = v3 > 0.f ? v3 : 0.f;
        if (MODE == 2) {
            v0 += b2f(resid[base + 0]); v1 += b2f(resid[base + 1]);
            v2 += b2f(resid[base + 2]); v3 += b2f(resid[base + 3]);
        }
        outb[base + 0] = f2b(v0); outb[base + 1] = f2b(v1);
        outb[base + 2] = f2b(v2); outb[base + 3] = f2b(v3);
    }
}

// ---------------------------------------------------------------------------
// Fused al + softmax per (head, image), layer 3: 4 waves compute the 36
// per-node dots (al_s/al_d in LDS), 36 threads softmax -> alphaG.
// MEAN folds the 1/5 head-mean into alpha.
// ---------------------------------------------------------------------------
template<int H, int C, bool MEAN>
__global__ __launch_bounds__(256)
void al_alpha(const u16* __restrict__ h, const float* __restrict__ a_s,
              const float* __restrict__ a_d, float* __restrict__ alphaG)
{
    __shared__ float asl[36], adl[36];
    const int hd = blockIdx.x, b = blockIdx.y;
    const int nb = b * NOBJ;
    const int t = threadIdx.x, wv = t >> 6, lane = t & 63;
    constexpr int PL = C / 64;
    const float* asp = a_s + hd * C + lane * PL;
    const float* adp = a_d + hd * C + lane * PL;
    for (int n = wv; n < 36; n += 4) {
        const u16* hp = h + (size_t)(nb + n) * (H * C) + hd * C + lane * PL;
        u16 hb[PL];
        if constexpr (PL == 4) { *(uint2*)hb = *(const uint2*)hp; }
        else                   { *(uint4*)hb = *(const uint4*)hp; }
        float s1 = 0.f, s2 = 0.f;
        #pragma unroll
        for (int i = 0; i < PL; i++) {
            const float hv = b2f(hb[i]);
            s1 += hv * asp[i];
            s2 += hv * adp[i];
        }
        #pragma unroll
        for (int off = 32; off > 0; off >>= 1) {
            s1 += __shfl_down(s1, off);
            s2 += __shfl_down(s2, off);
        }
        if (lane == 0) { asl[n] = s1; adl[n] = s2; }
    }
    __syncthreads();
    if (t >= 36) return;
    const float ad = adl[t];
    float row[36];
    float mx = -1e30f;
    #pragma unroll
    for (int s = 0; s < 36; s++) {
        float v = asl[s] + ad; v = (v > 0.f) ? v : 0.2f * v;
        row[s] = v; mx = fmaxf(mx, v);
    }
    float sum = 0.f;
    #pragma unroll
    for (int s = 0; s < 36; s++) { row[s] = expf(row[s] - mx); sum += row[s]; }
    const float inv = (MEAN ? 0.2f : 1.0f) / (sum + 1e-16f);
    float* o = alphaG + (((size_t)b * H + hd) * 36 + t) * 36;
    #pragma unroll
    for (int s = 0; s < 36; s++) o[s] = row[s] * inv;
}

// ---------------------------------------------------------------------------
// Aggregation, mean layer (3): grid (512/64, B_IMG), 192 threads.
// Loops 5 heads, register-accumulates (0.2 folded into alpha), +b3 -> fp32.
// ---------------------------------------------------------------------------
__global__ __launch_bounds__(192)
void attn_agg_mean(const u16* __restrict__ h, const float* __restrict__ alphaG,
                   const float* __restrict__ b3, float* __restrict__ outp)
{
    __shared__ __align__(16) u16 hl[36 * 64];
    __shared__ float al[36 * 36];
    const int b = blockIdx.y, sl = blockIdx.x;
    const int nb = b * NOBJ, cb = sl * 64;
    const int t = threadIdx.x;

    float acc[3][4] = {};
    for (int hd = 0; hd < 5; hd++) {
        if (hd) __syncthreads();   // protect hl/al overwrite
        for (int e = t; e < 36 * 8; e += 192) {
            const int row = e >> 3, col = (e & 7) * 8;
            *(uint4*)&hl[row * 64 + col] =
                *(const uint4*)&h[(size_t)(nb + row) * 2560 + hd * 512 + cb + col];
        }
        const float* ap = alphaG + ((size_t)b * 5 + hd) * 1296;
        for (int e = t; e < 1296; e += 192) al[e] = ap[e];
        __syncthreads();
        #pragma unroll
        for (int p = 0; p < 3; p++) {
            const int e = p * 192 + t;
            const int d = e >> 4, c4 = (e & 15) * 4;
            for (int s = 0; s < 36; s++) {
                const float av = al[d * 36 + s];
                const ushort4 hv = *(const ushort4*)&hl[s * 64 + c4];
                acc[p][0] += av * b2f(hv.x); acc[p][1] += av * b2f(hv.y);
                acc[p][2] += av * b2f(hv.z); acc[p][3] += av * b2f(hv.w);
            }
        }
    }
    #pragma unroll
    for (int p = 0; p < 3; p++) {
        const int e = p * 192 + t;
        const int d = e >> 4, c4 = (e & 15) * 4;
        #pragma unroll
        for (int j = 0; j < 4; j++)
            outp[(size_t)(nb + d) * 512 + cb + c4 + j] = acc[p][j] + b3[cb + c4 + j];
    }
}

// ---------------------------------------------------------------------------
// Workspace ~65.3 MB, lifetime-packed (proven layout):
//  E: qe_c 0.66M | of_c 18.87M
//  A (23.59M): WqT(10.49)+qpart(5.24 @ +10.49) -> x -> g1 -> h3
//  B ( 9.44M): WvT(8.39), q(1.05 @ +8.39) -> W1T(4.19)|W2T(2.10 @ +4.19) -> g2
//  C ( 9.44M): h1 -> h2 -> W3T
//  F: alphaG 3.32M
// ---------------------------------------------------------------------------
extern "C" void kernel_launch(void* const* d_in, const int* in_sizes, int n_in,
                              void* d_out, int out_size, void* d_ws, size_t ws_size,
                              hipStream_t stream)
{
    const float* qe  = (const float*)d_in[0];    // [128,2400]
    const float* of  = (const float*)d_in[1];    // [4608,2048]
    const float* Wq  = (const float*)d_in[3];    // [2400,2048]
    const float* bq  = (const float*)d_in[4];
    const float* Wv  = (const float*)d_in[5];    // [2048,2048]
    const float* bv  = (const float*)d_in[6];
    const float* W1  = (const float*)d_in[7];    // [2048,1024]
    const float* a1s = (const float*)d_in[8];
    const float* a1d = (const float*)d_in[9];
    const float* b1  = (const float*)d_in[10];
    const float* W2  = (const float*)d_in[11];   // [1024,1024]
    const float* a2s = (const float*)d_in[12];
    const float* a2d = (const float*)d_in[13];
    const float* b2  = (const float*)d_in[14];
    const float* W3  = (const float*)d_in[15];   // [1024,2560]
    const float* a3s = (const float*)d_in[16];
    const float* a3d = (const float*)d_in[17];
    const float* b3  = (const float*)d_in[18];
    float* out = (float*)d_out;
    (void)ws_size; (void)in_sizes; (void)n_in; (void)out_size;

    char* W0 = (char*)d_ws;
    size_t off = 0;
    auto alloc = [&](size_t bytes) -> char* {
        char* p = W0 + off; off += (bytes + 255) & ~(size_t)255; return p;
    };
    u16* qe_c = (u16*)alloc(128ull * 2560 * 2);
    u16* of_c = (u16*)alloc(4608ull * 2048 * 2);
    const size_t szA = 4608ull * 2560 * 2;
    const size_t szB = 4608ull * 1024 * 2;
    const size_t szC = 4608ull * 1024 * 2;
    char* Abase = alloc(szA);
    char* Bbase = alloc(szB);
    char* Cbase = alloc(szC);
    float* alphaG = (float*)alloc(128ull * 5 * 36 * 36 * 4);   // 3.32 MB

    u16*   WqT   = (u16*)Abase;                           // [2048,2560]
    float* qpart = (float*)(Abase + 2048ull * 2560 * 2);
    u16*   x     = (u16*)Abase;
    u16*   g1    = (u16*)Abase;
    u16*   h3    = (u16*)Abase;
    u16*   WvT   = (u16*)Bbase;                           // [2048,2048]
    float* q     = (float*)(Bbase + 2048ull * 2048 * 2);
    u16*   W1T   = (u16*)Bbase;                           // [1024,2048]
    u16*   W2T   = (u16*)(Bbase + 1024ull * 2048 * 2);    // [1024,1024]
    u16*   g2    = (u16*)Bbase;
    u16*   h1    = (u16*)Cbase;
    u16*   h2    = (u16*)Cbase;
    u16*   W3T   = (u16*)Cbase;                           // [2560,1024]

    // S0: canonicalize activations to bf16 (qe K-padded to 2560)
    conv_all<<<dim3(9216 + 1280), 256, 0, stream>>>(of, of_c, qe, qe_c);

    // S1: transpose Wq (K-pad 2400->2560) + Wv in one launch
    transpose_cvt2<<<dim3(5120 + 4096), 256, 0, stream>>>(
        Wq, WqT, 2400, 2560, 2048, 5120,
        Wv, WvT, 2048, 2048, 2048);

    // S2-S3: q = qe @ Wq + bq   (splitK=5 x 512)
    gemm_tn<1><<<dim3(16, 1, 5), 256, 0, stream>>>(qe_c, WqT, 128, 2048, 2560, 512,
                                                   qpart, nullptr, nullptr, nullptr);
    qcombine<<<dim3(128 * 2048 / 256), 256, 0, stream>>>(qpart, bq, q, 128 * 2048, 5);

    // S4: x = (of @ Wv + bv) * q_rep
    gemm_tn<2><<<dim3(16, 36, 1), 256, 0, stream>>>(of_c, WvT, 4608, 2048, 2048, 2048,
                                                    nullptr, x, bv, q);

    // S5: transpose W1 + W2 in one launch
    transpose_cvt2<<<dim3(2048 + 1024), 256, 0, stream>>>(
        W1, W1T, 2048, 2048, 1024, 2048,
        W2, W2T, 1024, 1024, 1024);

    // S6-S7: layer 1 (fused attention)
    gemm_tn<0><<<dim3(8, 36, 1), 256, 0, stream>>>(x, W1T, 4608, 1024, 2048, 2048,
                                                   nullptr, h1, nullptr, nullptr);
    attn_kernel<4, 256, 1><<<dim3(4, B_IMG), 256, 0, stream>>>(h1, a1s, a1d, b1, nullptr, g1);

    // S8-S9: layer 2 (+ residual g1, fused attention)
    gemm_tn<0><<<dim3(8, 36, 1), 256, 0, stream>>>(g1, W2T, 4608, 1024, 1024, 1024,
                                                   nullptr, h2, nullptr, nullptr);
    attn_kernel<4, 256, 2><<<dim3(4, B_IMG), 256, 0, stream>>>(h2, a2s, a2d, b2, g1, g2);

    // S10-S13: layer 3 (5 heads, mean + b3) -> fp32 out
    transpose_cvt2<<<dim3(2560), 256, 0, stream>>>(
        W3, W3T, 1024, 1024, 2560, 2560,
        W3, W3T, 1024, 1024, 2560);
    gemm_tn<0><<<dim3(20, 36, 1), 256, 0, stream>>>(g2, W3T, 4608, 2560, 1024, 1024,
                                                    nullptr, h3, nullptr, nullptr);
    al_alpha<5, 512, true><<<dim3(5, B_IMG), 256, 0, stream>>>(h3, a3s, a3d, alphaG);
    attn_agg_mean<<<dim3(8, B_IMG), 192, 0, stream>>>(h3, alphaG, b3, out);
}

// Round 6
// 574.139 us; speedup vs baseline: 1.4005x; 1.4005x over previous
//
#include <hip/hip_runtime.h>
#include <hip/hip_bf16.h>

typedef unsigned short u16;
typedef __bf16 bf16x8 __attribute__((ext_vector_type(8)));
typedef float f32x4 __attribute__((ext_vector_type(4)));

#define B_IMG 128
#define NOBJ  36
#define NNODE (B_IMG * NOBJ)

__device__ __forceinline__ float b2f(u16 u) {
    union { unsigned int i; float f; } v; v.i = ((unsigned int)u) << 16; return v.f;
}
__device__ __forceinline__ u16 f2b(float f) {
    union { float f; unsigned int i; } v; v.f = f;
    unsigned int u = v.i;
    return (u16)((u + 0x7fffu + ((u >> 16) & 1u)) >> 16);   // RNE
}

// ---------------------------------------------------------------------------
// Merged activation convert: blocks [0,9216) pack of (fp32->bf16, x4/thread);
// blocks [9216,10496) pad-convert qe [128,2400] -> [128,2560] (zero cols>=2400).
// ---------------------------------------------------------------------------
__global__ __launch_bounds__(256)
void conv_all(const float* __restrict__ of, u16* __restrict__ of_c,
              const float* __restrict__ qe, u16* __restrict__ qe_c)
{
    const int bid = blockIdx.x;
    if (bid < 9216) {
        const int i = bid * 256 + threadIdx.x;   // < 4608*2048/4 exactly
        const float4 f = ((const float4*)of)[i];
        ushort4 o; o.x = f2b(f.x); o.y = f2b(f.y); o.z = f2b(f.z); o.w = f2b(f.w);
        ((ushort4*)of_c)[i] = o;
    } else {
        const int i = (bid - 9216) * 256 + threadIdx.x;  // < 128*2560 exactly
        const int r = i / 2560, c = i - r * 2560;
        qe_c[i] = (c < 2400) ? f2b(qe[r * 2400 + c]) : (u16)0;
    }
}

// ---------------------------------------------------------------------------
// Generic fused convert+transpose for TWO matrices in one launch.
// src [Rs, C] fp32 -> dst [C, Rd] bf16, rows k in [Rs, Rd) zero-filled.
// Tiles per matrix: (C/32) * (Rd/32); matrix 0 owns tiles [0, nt0).
// ---------------------------------------------------------------------------
__global__ __launch_bounds__(256)
void transpose_cvt2(const float* __restrict__ s0, u16* __restrict__ d0,
                    int Rs0, int Rd0, int C0, int nt0,
                    const float* __restrict__ s1, u16* __restrict__ d1,
                    int Rs1, int Rd1, int C1)
{
    __shared__ u16 tile[32][33];
    int tb = blockIdx.x;
    const float* src; u16* dst; int Rs, Rd, C;
    if (tb < nt0) { src = s0; dst = d0; Rs = Rs0; Rd = Rd0; C = C0; }
    else { tb -= nt0; src = s1; dst = d1; Rs = Rs1; Rd = Rd1; C = C1; }
    const int ntx = C >> 5;
    const int ty = tb / ntx, tx = tb - ty * ntx;
    const int bx = tx * 32, by = ty * 32;
    const int lx = threadIdx.x & 31, ly = threadIdx.x >> 5;   // 32x8
    #pragma unroll
    for (int i = ly; i < 32; i += 8) {
        const int k = by + i;
        tile[i][lx] = (k < Rs) ? f2b(src[(size_t)k * C + bx + lx]) : (u16)0;
    }
    __syncthreads();
    #pragma unroll
    for (int i = ly; i < 32; i += 8) dst[(size_t)(bx + i) * Rd + by + lx] = tile[lx][i];
}

// ---------------------------------------------------------------------------
// TN MFMA GEMM: C[M,N] = A[M,K] * Bt[N,K]^T   (bf16 in, fp32 acc)
// 128x128 tile, BK=32, 4 waves 2x2, per iter 4x4 16x16x32 MFMA.
// A-DIRECT (spill-safe): A fragments stream global->VGPR into NAMED scalar
// registers via macro (no pointer-taken arrays -> no scratch; r5's lambda
// pointer param caused 147 MB scratch traffic).  Register double-buffer
// aP*/aQ* with static names, manual unroll-2 (all call sites even nIter).
// LDS carries ONLY B: 2 stages x 8 KB = 16 KB.  Per-iter LDS pipe traffic
// drops 48 KB -> 24 KB (the measured MfmaUtil~25% matched the 48 KB model;
// ceiling now ~41%).  __launch_bounds__(256,3): 170-reg cap, no spill
// (need ~64 AGPR acc + ~60 VGPR live).
// EPI: 1 = splitK fp32 partial, 2 = +bias then *qmul -> bf16, 0 = bf16.
// ---------------------------------------------------------------------------
#define LOAD_A(d0, d1, d2, d3, itv)                                   \
    {                                                                 \
        const u16* p_ = gA + (size_t)(itv) * 32;                      \
        d0 = *(const bf16x8*)(p_);                                    \
        d1 = *(const bf16x8*)(p_ + aRow16);                           \
        d2 = *(const bf16x8*)(p_ + 2 * aRow16);                       \
        d3 = *(const bf16x8*)(p_ + 3 * aRow16);                       \
    }

#define COMPUTE(stv, A0, A1, A2, A3)                                  \
    {                                                                 \
        const int bo_ = (stv) * 4096;                                 \
        bf16x8 bv0 = *(const bf16x8*)&lds[bo_ + bfr[0]];              \
        bf16x8 bv1 = *(const bf16x8*)&lds[bo_ + bfr[1]];              \
        bf16x8 bv2 = *(const bf16x8*)&lds[bo_ + bfr[2]];              \
        bf16x8 bv3 = *(const bf16x8*)&lds[bo_ + bfr[3]];              \
        acc[0][0] = __builtin_amdgcn_mfma_f32_16x16x32_bf16(A0, bv0, acc[0][0], 0, 0, 0); \
        acc[0][1] = __builtin_amdgcn_mfma_f32_16x16x32_bf16(A0, bv1, acc[0][1], 0, 0, 0); \
        acc[0][2] = __builtin_amdgcn_mfma_f32_16x16x32_bf16(A0, bv2, acc[0][2], 0, 0, 0); \
        acc[0][3] = __builtin_amdgcn_mfma_f32_16x16x32_bf16(A0, bv3, acc[0][3], 0, 0, 0); \
        acc[1][0] = __builtin_amdgcn_mfma_f32_16x16x32_bf16(A1, bv0, acc[1][0], 0, 0, 0); \
        acc[1][1] = __builtin_amdgcn_mfma_f32_16x16x32_bf16(A1, bv1, acc[1][1], 0, 0, 0); \
        acc[1][2] = __builtin_amdgcn_mfma_f32_16x16x32_bf16(A1, bv2, acc[1][2], 0, 0, 0); \
        acc[1][3] = __builtin_amdgcn_mfma_f32_16x16x32_bf16(A1, bv3, acc[1][3], 0, 0, 0); \
        acc[2][0] = __builtin_amdgcn_mfma_f32_16x16x32_bf16(A2, bv0, acc[2][0], 0, 0, 0); \
        acc[2][1] = __builtin_amdgcn_mfma_f32_16x16x32_bf16(A2, bv1, acc[2][1], 0, 0, 0); \
        acc[2][2] = __builtin_amdgcn_mfma_f32_16x16x32_bf16(A2, bv2, acc[2][2], 0, 0, 0); \
        acc[2][3] = __builtin_amdgcn_mfma_f32_16x16x32_bf16(A2, bv3, acc[2][3], 0, 0, 0); \
        acc[3][0] = __builtin_amdgcn_mfma_f32_16x16x32_bf16(A3, bv0, acc[3][0], 0, 0, 0); \
        acc[3][1] = __builtin_amdgcn_mfma_f32_16x16x32_bf16(A3, bv1, acc[3][1], 0, 0, 0); \
        acc[3][2] = __builtin_amdgcn_mfma_f32_16x16x32_bf16(A3, bv2, acc[3][2], 0, 0, 0); \
        acc[3][3] = __builtin_amdgcn_mfma_f32_16x16x32_bf16(A3, bv3, acc[3][3], 0, 0, 0); \
    }

template<int EPI>
__global__ __launch_bounds__(256, 3)
void gemm_tn(const u16* __restrict__ A, const u16* __restrict__ Bt,
             int M, int N, int K, int kLen,
             float* __restrict__ Cf, u16* __restrict__ Cb,
             const float* __restrict__ bias, const float* __restrict__ qmul)
{
    __shared__ __align__(16) u16 lds[2 * 4096];   // 16 KB (B only)

    const int t    = threadIdx.x;
    const int lane = t & 63;
    const int wave = t >> 6;
    const int wr = wave >> 1, wc = wave & 1;
    const int quad = lane >> 4, l16 = lane & 15;
    const int rowBase = blockIdx.y * 128;
    const int colBase = blockIdx.x * 128;
    const int k0 = blockIdx.z * kLen;

    // B staging: wave w owns rows [w*32, w*32+32); 2 DMA chunks of 16 rows.
    const u16* gB0 = Bt + (size_t)(colBase + wave * 32 + (lane >> 2)) * K + k0 + (lane & 3) * 8;
    const u16* gB1 = gB0 + 16 * (size_t)K;
    const int ro = wave * 1024;   // 32 rows * 32 u16

    // A direct-to-reg base: frag r = row (wr*64 + r*16 + l16), cols quad*8..+8
    const u16* gA = A + (size_t)(rowBase + wr * 64 + l16) * K + k0 + quad * 8;
    const size_t aRow16 = (size_t)16 * K;

    int bfr[4];
    #pragma unroll
    for (int c = 0; c < 4; c++) bfr[c] = (wc * 64 + c * 16 + l16) * 32 + quad * 8;

    f32x4 acc[4][4];
    #pragma unroll
    for (int r = 0; r < 4; r++)
        #pragma unroll
        for (int c = 0; c < 4; c++)
            acc[r][c] = (f32x4){0.f, 0.f, 0.f, 0.f};

    auto gld = [](const u16* g, u16* s) {
        __builtin_amdgcn_global_load_lds(
            (const __attribute__((address_space(1))) void*)g,
            (__attribute__((address_space(3))) void*)s, 16, 0, 0);
    };
    auto dmaB = [&](int it, int st) {
        const int kk = it * 32;
        const int bo = st * 4096;
        gld(gB0 + kk, &lds[bo + ro]);
        gld(gB1 + kk, &lds[bo + ro + 512]);
    };

    const int nIter = kLen >> 5;   // even at all call sites (16/32/64)
    bf16x8 aP0, aP1, aP2, aP3, aQ0, aQ1, aQ2, aQ3;
    dmaB(0, 0);
    LOAD_A(aP0, aP1, aP2, aP3, 0);
    for (int it = 0; it < nIter; it += 2) {
        asm volatile("s_waitcnt vmcnt(0)\n\ts_barrier" ::: "memory");
        if (it + 1 < nIter) {
            dmaB(it + 1, 1);
            LOAD_A(aQ0, aQ1, aQ2, aQ3, it + 1);
        }
        COMPUTE(0, aP0, aP1, aP2, aP3);
        asm volatile("s_waitcnt vmcnt(0)\n\ts_barrier" ::: "memory");
        if (it + 2 < nIter) {
            dmaB(it + 2, 0);
            LOAD_A(aP0, aP1, aP2, aP3, it + 2);
        }
        COMPUTE(1, aQ0, aQ1, aQ2, aQ3);
    }

    // epilogue: D row = quad*4+reg, col = l16
    #pragma unroll
    for (int r = 0; r < 4; r++) {
        const int mBase = rowBase + wr * 64 + r * 16 + quad * 4;
        #pragma unroll
        for (int c = 0; c < 4; c++) {
            const int n = colBase + wc * 64 + c * 16 + l16;
            #pragma unroll
            for (int e = 0; e < 4; e++) {
                const int m = mBase + e;
                float v = acc[r][c][e];
                if (EPI == 1) {
                    Cf[((size_t)blockIdx.z * M + m) * N + n] = v;
                } else if (EPI == 2) {
                    v += bias[n];
                    v *= qmul[(size_t)(m / NOBJ) * N + n];
                    Cb[(size_t)m * N + n] = f2b(v);
                } else {
                    Cb[(size_t)m * N + n] = f2b(v);
                }
            }
        }
    }
}

// ---------------------------------------------------------------------------
__global__ __launch_bounds__(256)
void qcombine(const float* __restrict__ p, const float* __restrict__ bias,
              float* __restrict__ q, int MN, int S)
{
    const int i = blockIdx.x * 256 + threadIdx.x;
    float s = 0.f;
    for (int z = 0; z < S; z++) s += p[(size_t)z * MN + i];
    q[i] = s + bias[i & 2047];
}

// ---------------------------------------------------------------------------
// Fused attention per (image, head) — layers 1/2 (measured-best structure).
// MODE 1: relu(agg+b) -> g (bf16);  MODE 2: relu(agg+b)+resid -> g
// ---------------------------------------------------------------------------
template<int H, int C, int MODE>
__global__ __launch_bounds__(256)
void attn_kernel(const u16* __restrict__ h, const float* __restrict__ a_src,
                 const float* __restrict__ a_dst, const float* __restrict__ bias,
                 const u16* __restrict__ resid, u16* __restrict__ outb)
{
    __shared__ __align__(16) u16 hl[36 * C];
    __shared__ float alpha[36 * 36];
    __shared__ float asl[36], adl[36];
    __shared__ float psum[36][8][2];
    const int b = blockIdx.y, hd = blockIdx.x;
    const int t = threadIdx.x;
    const int nb = b * NOBJ;
    constexpr int CH = C / 8;
    for (int e = t; e < 36 * CH; e += 256) {
        const int row = e / CH, col = (e - row * CH) * 8;
        *(uint4*)&hl[row * C + col] = *(const uint4*)&h[(size_t)(nb + row) * (H * C) + hd * C + col];
    }
    __syncthreads();
    constexpr int SEG = C / 8;
    for (int e = t; e < 36 * 8; e += 256) {
        const int n = e >> 3, sg = e & 7;
        const u16*   hp = &hl[n * C + sg * SEG];
        const float* as = a_src + hd * C + sg * SEG;
        const float* ad = a_dst + hd * C + sg * SEG;
        float s1 = 0.f, s2 = 0.f;
        #pragma unroll 8
        for (int i = 0; i < SEG; i++) {
            const float hv = b2f(hp[i]);
            s1 += hv * as[i]; s2 += hv * ad[i];
        }
        psum[n][sg][0] = s1; psum[n][sg][1] = s2;
    }
    __syncthreads();
    if (t < 36) {
        float s1 = 0.f, s2 = 0.f;
        #pragma unroll
        for (int sg = 0; sg < 8; sg++) { s1 += psum[t][sg][0]; s2 += psum[t][sg][1]; }
        asl[t] = s1; adl[t] = s2;
    }
    __syncthreads();
    if (t < 36) {
        const float ad = adl[t];
        float mx = -1e30f;
        for (int s = 0; s < 36; s++) {
            float v = asl[s] + ad; v = (v > 0.f) ? v : 0.2f * v;
            alpha[t * 36 + s] = v; mx = fmaxf(mx, v);
        }
        float sum = 0.f;
        for (int s = 0; s < 36; s++) { const float ex = expf(alpha[t * 36 + s] - mx); alpha[t * 36 + s] = ex; sum += ex; }
        const float inv = 1.f / (sum + 1e-16f);
        for (int s = 0; s < 36; s++) alpha[t * 36 + s] *= inv;
    }
    __syncthreads();
    constexpr int NC4 = C / 4;
    for (int e = t; e < 36 * NC4; e += 256) {
        const int d = e / NC4, c4 = (e - d * NC4) * 4;
        float a0 = 0, a1 = 0, a2 = 0, a3 = 0;
        for (int s = 0; s < 36; s++) {
            const float al = alpha[d * 36 + s];
            const ushort4 hv = *(const ushort4*)&hl[s * C + c4];
            a0 += al * b2f(hv.x); a1 += al * b2f(hv.y); a2 += al * b2f(hv.z); a3 += al * b2f(hv.w);
        }
        const int n = nb + d;
        const size_t base = (size_t)n * (H * C) + hd * C + c4;
        const int bb = hd * C + c4;
        float v0 = a0 + bias[bb + 0];
        float v1 = a1 + bias[bb + 1];
        float v2 = a2 + bias[bb + 2];
        float v3 = a3 + bias[bb + 3];
        v0 = v0 > 0.f ? v0 : 0.f; v1 = v1 > 0.f ? v1 : 0.f;
        v2 = v2 > 0.f ? v2 : 0.f; v3 = v3 > 0.f ? v3 : 0.f;
        if (MODE == 2) {
            v0 += b2f(resid[base + 0]); v1 += b2f(resid[base + 1]);
            v2 += b2f(resid[base + 2]); v3 += b2f(resid[base + 3]);
        }
        outb[base + 0] = f2b(v0); outb[base + 1] = f2b(v1);
        outb[base + 2] = f2b(v2); outb[base + 3] = f2b(v3);
    }
}

// ---------------------------------------------------------------------------
// Fused al + softmax per (head, image), layer 3: 4 waves compute the 36
// per-node dots (al_s/al_d in LDS), 36 threads softmax -> alphaG.
// MEAN folds the 1/5 head-mean into alpha.
// ---------------------------------------------------------------------------
template<int H, int C, bool MEAN>
__global__ __launch_bounds__(256)
void al_alpha(const u16* __restrict__ h, const float* __restrict__ a_s,
              const float* __restrict__ a_d, float* __restrict__ alphaG)
{
    __shared__ float asl[36], adl[36];
    const int hd = blockIdx.x, b = blockIdx.y;
    const int nb = b * NOBJ;
    const int t = threadIdx.x, wv = t >> 6, lane = t & 63;
    constexpr int PL = C / 64;
    const float* asp = a_s + hd * C + lane * PL;
    const float* adp = a_d + hd * C + lane * PL;
    for (int n = wv; n < 36; n += 4) {
        const u16* hp = h + (size_t)(nb + n) * (H * C) + hd * C + lane * PL;
        u16 hb[PL];
        if constexpr (PL == 4) { *(uint2*)hb = *(const uint2*)hp; }
        else                   { *(uint4*)hb = *(const uint4*)hp; }
        float s1 = 0.f, s2 = 0.f;
        #pragma unroll
        for (int i = 0; i < PL; i++) {
            const float hv = b2f(hb[i]);
            s1 += hv * asp[i];
            s2 += hv * adp[i];
        }
        #pragma unroll
        for (int off = 32; off > 0; off >>= 1) {
            s1 += __shfl_down(s1, off);
            s2 += __shfl_down(s2, off);
        }
        if (lane == 0) { asl[n] = s1; adl[n] = s2; }
    }
    __syncthreads();
    if (t >= 36) return;
    const float ad = adl[t];
    float row[36];
    float mx = -1e30f;
    #pragma unroll
    for (int s = 0; s < 36; s++) {
        float v = asl[s] + ad; v = (v > 0.f) ? v : 0.2f * v;
        row[s] = v; mx = fmaxf(mx, v);
    }
    float sum = 0.f;
    #pragma unroll
    for (int s = 0; s < 36; s++) { row[s] = expf(row[s] - mx); sum += row[s]; }
    const float inv = (MEAN ? 0.2f : 1.0f) / (sum + 1e-16f);
    float* o = alphaG + (((size_t)b * H + hd) * 36 + t) * 36;
    #pragma unroll
    for (int s = 0; s < 36; s++) o[s] = row[s] * inv;
}

// ---------------------------------------------------------------------------
// Aggregation, mean layer (3): grid (512/64, B_IMG), 192 threads.
// Loops 5 heads, register-accumulates (0.2 folded into alpha), +b3 -> fp32.
// ---------------------------------------------------------------------------
__global__ __launch_bounds__(192)
void attn_agg_mean(const u16* __restrict__ h, const float* __restrict__ alphaG,
                   const float* __restrict__ b3, float* __restrict__ outp)
{
    __shared__ __align__(16) u16 hl[36 * 64];
    __shared__ float al[36 * 36];
    const int b = blockIdx.y, sl = blockIdx.x;
    const int nb = b * NOBJ, cb = sl * 64;
    const int t = threadIdx.x;

    float acc[3][4] = {};
    for (int hd = 0; hd < 5; hd++) {
        if (hd) __syncthreads();   // protect hl/al overwrite
        for (int e = t; e < 36 * 8; e += 192) {
            const int row = e >> 3, col = (e & 7) * 8;
            *(uint4*)&hl[row * 64 + col] =
                *(const uint4*)&h[(size_t)(nb + row) * 2560 + hd * 512 + cb + col];
        }
        const float* ap = alphaG + ((size_t)b * 5 + hd) * 1296;
        for (int e = t; e < 1296; e += 192) al[e] = ap[e];
        __syncthreads();
        #pragma unroll
        for (int p = 0; p < 3; p++) {
            const int e = p * 192 + t;
            const int d = e >> 4, c4 = (e & 15) * 4;
            for (int s = 0; s < 36; s++) {
                const float av = al[d * 36 + s];
                const ushort4 hv = *(const ushort4*)&hl[s * 64 + c4];
                acc[p][0] += av * b2f(hv.x); acc[p][1] += av * b2f(hv.y);
                acc[p][2] += av * b2f(hv.z); acc[p][3] += av * b2f(hv.w);
            }
        }
    }
    #pragma unroll
    for (int p = 0; p < 3; p++) {
        const int e = p * 192 + t;
        const int d = e >> 4, c4 = (e & 15) * 4;
        #pragma unroll
        for (int j = 0; j < 4; j++)
            outp[(size_t)(nb + d) * 512 + cb + c4 + j] = acc[p][j] + b3[cb + c4 + j];
    }
}

// ---------------------------------------------------------------------------
// Workspace ~65.3 MB, lifetime-packed (proven layout):
//  E: qe_c 0.66M | of_c 18.87M
//  A (23.59M): WqT(10.49)+qpart(5.24 @ +10.49) -> x -> g1 -> h3
//  B ( 9.44M): WvT(8.39), q(1.05 @ +8.39) -> W1T(4.19)|W2T(2.10 @ +4.19) -> g2
//  C ( 9.44M): h1 -> h2 -> W3T
//  F: alphaG 3.32M
// ---------------------------------------------------------------------------
extern "C" void kernel_launch(void* const* d_in, const int* in_sizes, int n_in,
                              void* d_out, int out_size, void* d_ws, size_t ws_size,
                              hipStream_t stream)
{
    const float* qe  = (const float*)d_in[0];    // [128,2400]
    const float* of  = (const float*)d_in[1];    // [4608,2048]
    const float* Wq  = (const float*)d_in[3];    // [2400,2048]
    const float* bq  = (const float*)d_in[4];
    const float* Wv  = (const float*)d_in[5];    // [2048,2048]
    const float* bv  = (const float*)d_in[6];
    const float* W1  = (const float*)d_in[7];    // [2048,1024]
    const float* a1s = (const float*)d_in[8];
    const float* a1d = (const float*)d_in[9];
    const float* b1  = (const float*)d_in[10];
    const float* W2  = (const float*)d_in[11];   // [1024,1024]
    const float* a2s = (const float*)d_in[12];
    const float* a2d = (const float*)d_in[13];
    const float* b2  = (const float*)d_in[14];
    const float* W3  = (const float*)d_in[15];   // [1024,2560]
    const float* a3s = (const float*)d_in[16];
    const float* a3d = (const float*)d_in[17];
    const float* b3  = (const float*)d_in[18];
    float* out = (float*)d_out;
    (void)ws_size; (void)in_sizes; (void)n_in; (void)out_size;

    char* W0 = (char*)d_ws;
    size_t off = 0;
    auto alloc = [&](size_t bytes) -> char* {
        char* p = W0 + off; off += (bytes + 255) & ~(size_t)255; return p;
    };
    u16* qe_c = (u16*)alloc(128ull * 2560 * 2);
    u16* of_c = (u16*)alloc(4608ull * 2048 * 2);
    const size_t szA = 4608ull * 2560 * 2;
    const size_t szB = 4608ull * 1024 * 2;
    const size_t szC = 4608ull * 1024 * 2;
    char* Abase = alloc(szA);
    char* Bbase = alloc(szB);
    char* Cbase = alloc(szC);
    float* alphaG = (float*)alloc(128ull * 5 * 36 * 36 * 4);   // 3.32 MB

    u16*   WqT   = (u16*)Abase;                           // [2048,2560]
    float* qpart = (float*)(Abase + 2048ull * 2560 * 2);
    u16*   x     = (u16*)Abase;
    u16*   g1    = (u16*)Abase;
    u16*   h3    = (u16*)Abase;
    u16*   WvT   = (u16*)Bbase;                           // [2048,2048]
    float* q     = (float*)(Bbase + 2048ull * 2048 * 2);
    u16*   W1T   = (u16*)Bbase;                           // [1024,2048]
    u16*   W2T   = (u16*)(Bbase + 1024ull * 2048 * 2);    // [1024,1024]
    u16*   g2    = (u16*)Bbase;
    u16*   h1    = (u16*)Cbase;
    u16*   h2    = (u16*)Cbase;
    u16*   W3T   = (u16*)Cbase;                           // [2560,1024]

    // S0: canonicalize activations to bf16 (qe K-padded to 2560)
    conv_all<<<dim3(9216 + 1280), 256, 0, stream>>>(of, of_c, qe, qe_c);

    // S1: transpose Wq (K-pad 2400->2560) + Wv in one launch
    transpose_cvt2<<<dim3(5120 + 4096), 256, 0, stream>>>(
        Wq, WqT, 2400, 2560, 2048, 5120,
        Wv, WvT, 2048, 2048, 2048);

    // S2-S3: q = qe @ Wq + bq   (splitK=5 x 512)
    gemm_tn<1><<<dim3(16, 1, 5), 256, 0, stream>>>(qe_c, WqT, 128, 2048, 2560, 512,
                                                   qpart, nullptr, nullptr, nullptr);
    qcombine<<<dim3(128 * 2048 / 256), 256, 0, stream>>>(qpart, bq, q, 128 * 2048, 5);

    // S4: x = (of @ Wv + bv) * q_rep
    gemm_tn<2><<<dim3(16, 36, 1), 256, 0, stream>>>(of_c, WvT, 4608, 2048, 2048, 2048,
                                                    nullptr, x, bv, q);

    // S5: transpose W1 + W2 in one launch
    transpose_cvt2<<<dim3(2048 + 1024), 256, 0, stream>>>(
        W1, W1T, 2048, 2048, 1024, 2048,
        W2, W2T, 1024, 1024, 1024);

    // S6-S7: layer 1 (fused attention)
    gemm_tn<0><<<dim3(8, 36, 1), 256, 0, stream>>>(x, W1T, 4608, 1024, 2048, 2048,
                                                   nullptr, h1, nullptr, nullptr);
    attn_kernel<4, 256, 1><<<dim3(4, B_IMG), 256, 0, stream>>>(h1, a1s, a1d, b1, nullptr, g1);

    // S8-S9: layer 2 (+ residual g1, fused attention)
    gemm_tn<0><<<dim3(8, 36, 1), 256, 0, stream>>>(g1, W2T, 4608, 1024, 1024, 1024,
                                                   nullptr, h2, nullptr, nullptr);
    attn_kernel<4, 256, 2><<<dim3(4, B_IMG), 256, 0, stream>>>(h2, a2s, a2d, b2, g1, g2);

    // S10-S13: layer 3 (5 heads, mean + b3) -> fp32 out
    transpose_cvt2<<<dim3(2560), 256, 0, stream>>>(
        W3, W3T, 1024, 1024, 2560, 2560,
        W3, W3T, 1024, 1024, 2560);
    gemm_tn<0><<<dim3(20, 36, 1), 256, 0, stream>>>(g2, W3T, 4608, 2560, 1024, 1024,
                                                    nullptr, h3, nullptr, nullptr);
    al_alpha<5, 512, true><<<dim3(5, B_IMG), 256, 0, stream>>>(h3, a3s, a3d, alphaG);
    attn_agg_mean<<<dim3(8, B_IMG), 192, 0, stream>>>(h3, alphaG, b3, out);
}

// Round 7
// 433.764 us; speedup vs baseline: 1.8537x; 1.3236x over previous
//
#include <hip/hip_runtime.h>
#include <hip/hip_bf16.h>

typedef unsigned short u16;
typedef __bf16 bf16x8 __attribute__((ext_vector_type(8)));
typedef float f32x4 __attribute__((ext_vector_type(4)));

#define B_IMG 128
#define NOBJ  36
#define NNODE (B_IMG * NOBJ)

__device__ __forceinline__ float b2f(u16 u) {
    union { unsigned int i; float f; } v; v.i = ((unsigned int)u) << 16; return v.f;
}
__device__ __forceinline__ u16 f2b(float f) {
    union { float f; unsigned int i; } v; v.f = f;
    unsigned int u = v.i;
    return (u16)((u + 0x7fffu + ((u >> 16) & 1u)) >> 16);   // RNE
}

// ---------------------------------------------------------------------------
// Merged activation convert: blocks [0,9216) pack of (fp32->bf16, x4/thread);
// blocks [9216,10496) pad-convert qe [128,2400] -> [128,2560] (zero cols>=2400).
// ---------------------------------------------------------------------------
__global__ __launch_bounds__(256)
void conv_all(const float* __restrict__ of, u16* __restrict__ of_c,
              const float* __restrict__ qe, u16* __restrict__ qe_c)
{
    const int bid = blockIdx.x;
    if (bid < 9216) {
        const int i = bid * 256 + threadIdx.x;   // < 4608*2048/4 exactly
        const float4 f = ((const float4*)of)[i];
        ushort4 o; o.x = f2b(f.x); o.y = f2b(f.y); o.z = f2b(f.z); o.w = f2b(f.w);
        ((ushort4*)of_c)[i] = o;
    } else {
        const int i = (bid - 9216) * 256 + threadIdx.x;  // < 128*2560 exactly
        const int r = i / 2560, c = i - r * 2560;
        qe_c[i] = (c < 2400) ? f2b(qe[r * 2400 + c]) : (u16)0;
    }
}

// ---------------------------------------------------------------------------
// Generic fused convert+transpose for TWO matrices in one launch.
// src [Rs, C] fp32 -> dst [C, Rd] bf16, rows k in [Rs, Rd) zero-filled.
// Tiles per matrix: (C/32) * (Rd/32); matrix 0 owns tiles [0, nt0).
// ---------------------------------------------------------------------------
__global__ __launch_bounds__(256)
void transpose_cvt2(const float* __restrict__ s0, u16* __restrict__ d0,
                    int Rs0, int Rd0, int C0, int nt0,
                    const float* __restrict__ s1, u16* __restrict__ d1,
                    int Rs1, int Rd1, int C1)
{
    __shared__ u16 tile[32][33];
    int tb = blockIdx.x;
    const float* src; u16* dst; int Rs, Rd, C;
    if (tb < nt0) { src = s0; dst = d0; Rs = Rs0; Rd = Rd0; C = C0; }
    else { tb -= nt0; src = s1; dst = d1; Rs = Rs1; Rd = Rd1; C = C1; }
    const int ntx = C >> 5;
    const int ty = tb / ntx, tx = tb - ty * ntx;
    const int bx = tx * 32, by = ty * 32;
    const int lx = threadIdx.x & 31, ly = threadIdx.x >> 5;   // 32x8
    #pragma unroll
    for (int i = ly; i < 32; i += 8) {
        const int k = by + i;
        tile[i][lx] = (k < Rs) ? f2b(src[(size_t)k * C + bx + lx]) : (u16)0;
    }
    __syncthreads();
    #pragma unroll
    for (int i = ly; i < 32; i += 8) dst[(size_t)(bx + i) * Rd + by + lx] = tile[lx][i];
}

// ---------------------------------------------------------------------------
// TN MFMA GEMM: C[M,N] = A[M,K] * Bt[N,K]^T   (bf16 in, fp32 acc)
// Proven-best structure (r2 measured: 58.6us S4, MfmaUtil 26.5%):
// 128x128 tile, BK=32, 4 waves 2x2, per iter 4x4 16x16x32 MFMA,
// A+B staged via global_load_lds, 2 stages = 32 KB LDS, vmcnt(0)+barrier/iter.
// NEW: bijective XCD-aware block swizzle (T1) — each XCD gets a contiguous
// run of ~nwg/8 blocks => blocks sharing an A row-panel co-reside on one
// XCD L2 (panel set ~2.25 MB fits 4 MB).  All call-site grids have
// gridDim.x*gridDim.y % 8 == 0 (576/288/720/16).
// EPI: 1 = splitK fp32 partial, 2 = +bias then *qmul -> bf16, 0 = bf16.
// ---------------------------------------------------------------------------
template<int EPI>
__global__ __launch_bounds__(256, 4)
void gemm_tn(const u16* __restrict__ A, const u16* __restrict__ Bt,
             int M, int N, int K, int kLen,
             float* __restrict__ Cf, u16* __restrict__ Cb,
             const float* __restrict__ bias, const float* __restrict__ qmul)
{
    __shared__ __align__(16) u16 lds[2 * 8192];   // 32 KB

    const int t    = threadIdx.x;
    const int lane = t & 63;
    const int wave = t >> 6;
    const int wr = wave >> 1, wc = wave & 1;
    const int quad = lane >> 4, l16 = lane & 15;

    // XCD swizzle: contiguous chunk of the xy-grid per XCD (bijective: nxy%8==0)
    const int nxy = gridDim.x * gridDim.y;
    int bid = blockIdx.x + gridDim.x * blockIdx.y;
    const int cpx = nxy >> 3;
    bid = (bid & 7) * cpx + (bid >> 3);
    const int bx = bid % gridDim.x, by = bid / gridDim.x;

    const int rowBase = by * 128;
    const int colBase = bx * 128;
    const int k0 = blockIdx.z * kLen;

    // staging: wave w owns rows [w*32, w*32+32); 2 DMA chunks of 16 rows per matrix.
    const u16* gA0 = A  + (size_t)(rowBase + wave * 32 + (lane >> 2)) * K + k0 + (lane & 3) * 8;
    const u16* gA1 = gA0 + 16 * (size_t)K;
    const u16* gB0 = Bt + (size_t)(colBase + wave * 32 + (lane >> 2)) * K + k0 + (lane & 3) * 8;
    const u16* gB1 = gB0 + 16 * (size_t)K;
    const int ro = wave * 1024;   // 32 rows * 32 u16

    int afr[4], bfr[4];
    #pragma unroll
    for (int r = 0; r < 4; r++) afr[r] = (wr * 64 + r * 16 + l16) * 32 + quad * 8;
    #pragma unroll
    for (int c = 0; c < 4; c++) bfr[c] = 4096 + (wc * 64 + c * 16 + l16) * 32 + quad * 8;

    f32x4 acc[4][4];
    #pragma unroll
    for (int r = 0; r < 4; r++)
        #pragma unroll
        for (int c = 0; c < 4; c++)
            acc[r][c] = (f32x4){0.f, 0.f, 0.f, 0.f};

    auto gld = [](const u16* g, u16* s) {
        __builtin_amdgcn_global_load_lds(
            (const __attribute__((address_space(1))) void*)g,
            (__attribute__((address_space(3))) void*)s, 16, 0, 0);
    };
    auto dma_stage = [&](int it, int st) {
        const int kk = it * 32;
        const int bo = st * 8192;
        gld(gA0 + kk, &lds[bo + ro]);
        gld(gA1 + kk, &lds[bo + ro + 512]);
        gld(gB0 + kk, &lds[bo + 4096 + ro]);
        gld(gB1 + kk, &lds[bo + 4096 + ro + 512]);
    };

    const int nIter = kLen >> 5;   // kLen % 32 == 0 at all call sites
    dma_stage(0, 0);

    for (int it = 0; it < nIter; ++it) {
        asm volatile("s_waitcnt vmcnt(0)\n\ts_barrier" ::: "memory");
        if (it + 1 < nIter) dma_stage(it + 1, (it + 1) & 1);
        const int bo = (it & 1) * 8192;
        bf16x8 avf[4], bvf[4];
        #pragma unroll
        for (int r = 0; r < 4; r++) avf[r] = *(const bf16x8*)&lds[bo + afr[r]];
        #pragma unroll
        for (int c = 0; c < 4; c++) bvf[c] = *(const bf16x8*)&lds[bo + bfr[c]];
        #pragma unroll
        for (int r = 0; r < 4; r++)
            #pragma unroll
            for (int c = 0; c < 4; c++)
                acc[r][c] = __builtin_amdgcn_mfma_f32_16x16x32_bf16(avf[r], bvf[c], acc[r][c], 0, 0, 0);
    }

    // epilogue: D row = quad*4+reg, col = l16
    #pragma unroll
    for (int r = 0; r < 4; r++) {
        const int mBase = rowBase + wr * 64 + r * 16 + quad * 4;
        #pragma unroll
        for (int c = 0; c < 4; c++) {
            const int n = colBase + wc * 64 + c * 16 + l16;
            #pragma unroll
            for (int e = 0; e < 4; e++) {
                const int m = mBase + e;
                float v = acc[r][c][e];
                if (EPI == 1) {
                    Cf[((size_t)blockIdx.z * M + m) * N + n] = v;
                } else if (EPI == 2) {
                    v += bias[n];
                    v *= qmul[(size_t)(m / NOBJ) * N + n];
                    Cb[(size_t)m * N + n] = f2b(v);
                } else {
                    Cb[(size_t)m * N + n] = f2b(v);
                }
            }
        }
    }
}

// ---------------------------------------------------------------------------
__global__ __launch_bounds__(256)
void qcombine(const float* __restrict__ p, const float* __restrict__ bias,
              float* __restrict__ q, int MN, int S)
{
    const int i = blockIdx.x * 256 + threadIdx.x;
    float s = 0.f;
    for (int z = 0; z < S; z++) s += p[(size_t)z * MN + i];
    q[i] = s + bias[i & 2047];
}

// ---------------------------------------------------------------------------
// Fused attention per (image, head) — layers 1/2 (measured-best structure).
// MODE 1: relu(agg+b) -> g (bf16);  MODE 2: relu(agg+b)+resid -> g
// ---------------------------------------------------------------------------
template<int H, int C, int MODE>
__global__ __launch_bounds__(256)
void attn_kernel(const u16* __restrict__ h, const float* __restrict__ a_src,
                 const float* __restrict__ a_dst, const float* __restrict__ bias,
                 const u16* __restrict__ resid, u16* __restrict__ outb)
{
    __shared__ __align__(16) u16 hl[36 * C];
    __shared__ float alpha[36 * 36];
    __shared__ float asl[36], adl[36];
    __shared__ float psum[36][8][2];
    const int b = blockIdx.y, hd = blockIdx.x;
    const int t = threadIdx.x;
    const int nb = b * NOBJ;
    constexpr int CH = C / 8;
    for (int e = t; e < 36 * CH; e += 256) {
        const int row = e / CH, col = (e - row * CH) * 8;
        *(uint4*)&hl[row * C + col] = *(const uint4*)&h[(size_t)(nb + row) * (H * C) + hd * C + col];
    }
    __syncthreads();
    constexpr int SEG = C / 8;
    for (int e = t; e < 36 * 8; e += 256) {
        const int n = e >> 3, sg = e & 7;
        const u16*   hp = &hl[n * C + sg * SEG];
        const float* as = a_src + hd * C + sg * SEG;
        const float* ad = a_dst + hd * C + sg * SEG;
        float s1 = 0.f, s2 = 0.f;
        #pragma unroll 8
        for (int i = 0; i < SEG; i++) {
            const float hv = b2f(hp[i]);
            s1 += hv * as[i]; s2 += hv * ad[i];
        }
        psum[n][sg][0] = s1; psum[n][sg][1] = s2;
    }
    __syncthreads();
    if (t < 36) {
        float s1 = 0.f, s2 = 0.f;
        #pragma unroll
        for (int sg = 0; sg < 8; sg++) { s1 += psum[t][sg][0]; s2 += psum[t][sg][1]; }
        asl[t] = s1; adl[t] = s2;
    }
    __syncthreads();
    if (t < 36) {
        const float ad = adl[t];
        float mx = -1e30f;
        for (int s = 0; s < 36; s++) {
            float v = asl[s] + ad; v = (v > 0.f) ? v : 0.2f * v;
            alpha[t * 36 + s] = v; mx = fmaxf(mx, v);
        }
        float sum = 0.f;
        for (int s = 0; s < 36; s++) { const float ex = expf(alpha[t * 36 + s] - mx); alpha[t * 36 + s] = ex; sum += ex; }
        const float inv = 1.f / (sum + 1e-16f);
        for (int s = 0; s < 36; s++) alpha[t * 36 + s] *= inv;
    }
    __syncthreads();
    constexpr int NC4 = C / 4;
    for (int e = t; e < 36 * NC4; e += 256) {
        const int d = e / NC4, c4 = (e - d * NC4) * 4;
        float a0 = 0, a1 = 0, a2 = 0, a3 = 0;
        for (int s = 0; s < 36; s++) {
            const float al = alpha[d * 36 + s];
            const ushort4 hv = *(const ushort4*)&hl[s * C + c4];
            a0 += al * b2f(hv.x); a1 += al * b2f(hv.y); a2 += al * b2f(hv.z); a3 += al * b2f(hv.w);
        }
        const int n = nb + d;
        const size_t base = (size_t)n * (H * C) + hd * C + c4;
        const int bb = hd * C + c4;
        float v0 = a0 + bias[bb + 0];
        float v1 = a1 + bias[bb + 1];
        float v2 = a2 + bias[bb + 2];
        float v3 = a3 + bias[bb + 3];
        v0 = v0 > 0.f ? v0 : 0.f; v1 = v1 > 0.f ? v1 : 0.f;
        v2 = v2 > 0.f ? v2 : 0.f; v3 = v3 > 0.f ? v3 : 0.f;
        if (MODE == 2) {
            v0 += b2f(resid[base + 0]); v1 += b2f(resid[base + 1]);
            v2 += b2f(resid[base + 2]); v3 += b2f(resid[base + 3]);
        }
        outb[base + 0] = f2b(v0); outb[base + 1] = f2b(v1);
        outb[base + 2] = f2b(v2); outb[base + 3] = f2b(v3);
    }
}

// ---------------------------------------------------------------------------
// Fused al + softmax per (head, image), layer 3: 4 waves compute the 36
// per-node dots (al_s/al_d in LDS), 36 threads softmax -> alphaG.
// MEAN folds the 1/5 head-mean into alpha.
// ---------------------------------------------------------------------------
template<int H, int C, bool MEAN>
__global__ __launch_bounds__(256)
void al_alpha(const u16* __restrict__ h, const float* __restrict__ a_s,
              const float* __restrict__ a_d, float* __restrict__ alphaG)
{
    __shared__ float asl[36], adl[36];
    const int hd = blockIdx.x, b = blockIdx.y;
    const int nb = b * NOBJ;
    const int t = threadIdx.x, wv = t >> 6, lane = t & 63;
    constexpr int PL = C / 64;
    const float* asp = a_s + hd * C + lane * PL;
    const float* adp = a_d + hd * C + lane * PL;
    for (int n = wv; n < 36; n += 4) {
        const u16* hp = h + (size_t)(nb + n) * (H * C) + hd * C + lane * PL;
        u16 hb[PL];
        if constexpr (PL == 4) { *(uint2*)hb = *(const uint2*)hp; }
        else                   { *(uint4*)hb = *(const uint4*)hp; }
        float s1 = 0.f, s2 = 0.f;
        #pragma unroll
        for (int i = 0; i < PL; i++) {
            const float hv = b2f(hb[i]);
            s1 += hv * asp[i];
            s2 += hv * adp[i];
        }
        #pragma unroll
        for (int off = 32; off > 0; off >>= 1) {
            s1 += __shfl_down(s1, off);
            s2 += __shfl_down(s2, off);
        }
        if (lane == 0) { asl[n] = s1; adl[n] = s2; }
    }
    __syncthreads();
    if (t >= 36) return;
    const float ad = adl[t];
    float row[36];
    float mx = -1e30f;
    #pragma unroll
    for (int s = 0; s < 36; s++) {
        float v = asl[s] + ad; v = (v > 0.f) ? v : 0.2f * v;
        row[s] = v; mx = fmaxf(mx, v);
    }
    float sum = 0.f;
    #pragma unroll
    for (int s = 0; s < 36; s++) { row[s] = expf(row[s] - mx); sum += row[s]; }
    const float inv = (MEAN ? 0.2f : 1.0f) / (sum + 1e-16f);
    float* o = alphaG + (((size_t)b * H + hd) * 36 + t) * 36;
    #pragma unroll
    for (int s = 0; s < 36; s++) o[s] = row[s] * inv;
}

// ---------------------------------------------------------------------------
// Aggregation, mean layer (3): grid (512/64, B_IMG), 192 threads.
// Loops 5 heads, register-accumulates (0.2 folded into alpha), +b3 -> fp32.
// ---------------------------------------------------------------------------
__global__ __launch_bounds__(192)
void attn_agg_mean(const u16* __restrict__ h, const float* __restrict__ alphaG,
                   const float* __restrict__ b3, float* __restrict__ outp)
{
    __shared__ __align__(16) u16 hl[36 * 64];
    __shared__ float al[36 * 36];
    const int b = blockIdx.y, sl = blockIdx.x;
    const int nb = b * NOBJ, cb = sl * 64;
    const int t = threadIdx.x;

    float acc[3][4] = {};
    for (int hd = 0; hd < 5; hd++) {
        if (hd) __syncthreads();   // protect hl/al overwrite
        for (int e = t; e < 36 * 8; e += 192) {
            const int row = e >> 3, col = (e & 7) * 8;
            *(uint4*)&hl[row * 64 + col] =
                *(const uint4*)&h[(size_t)(nb + row) * 2560 + hd * 512 + cb + col];
        }
        const float* ap = alphaG + ((size_t)b * 5 + hd) * 1296;
        for (int e = t; e < 1296; e += 192) al[e] = ap[e];
        __syncthreads();
        #pragma unroll
        for (int p = 0; p < 3; p++) {
            const int e = p * 192 + t;
            const int d = e >> 4, c4 = (e & 15) * 4;
            for (int s = 0; s < 36; s++) {
                const float av = al[d * 36 + s];
                const ushort4 hv = *(const ushort4*)&hl[s * 64 + c4];
                acc[p][0] += av * b2f(hv.x); acc[p][1] += av * b2f(hv.y);
                acc[p][2] += av * b2f(hv.z); acc[p][3] += av * b2f(hv.w);
            }
        }
    }
    #pragma unroll
    for (int p = 0; p < 3; p++) {
        const int e = p * 192 + t;
        const int d = e >> 4, c4 = (e & 15) * 4;
        #pragma unroll
        for (int j = 0; j < 4; j++)
            outp[(size_t)(nb + d) * 512 + cb + c4 + j] = acc[p][j] + b3[cb + c4 + j];
    }
}

// ---------------------------------------------------------------------------
// Workspace ~65.3 MB, lifetime-packed (proven layout):
//  E: qe_c 0.66M | of_c 18.87M
//  A (23.59M): WqT(10.49)+qpart(5.24 @ +10.49) -> x -> g1 -> h3
//  B ( 9.44M): WvT(8.39), q(1.05 @ +8.39) -> W1T(4.19)|W2T(2.10 @ +4.19) -> g2
//  C ( 9.44M): h1 -> h2 -> W3T
//  F: alphaG 3.32M
// ---------------------------------------------------------------------------
extern "C" void kernel_launch(void* const* d_in, const int* in_sizes, int n_in,
                              void* d_out, int out_size, void* d_ws, size_t ws_size,
                              hipStream_t stream)
{
    const float* qe  = (const float*)d_in[0];    // [128,2400]
    const float* of  = (const float*)d_in[1];    // [4608,2048]
    const float* Wq  = (const float*)d_in[3];    // [2400,2048]
    const float* bq  = (const float*)d_in[4];
    const float* Wv  = (const float*)d_in[5];    // [2048,2048]
    const float* bv  = (const float*)d_in[6];
    const float* W1  = (const float*)d_in[7];    // [2048,1024]
    const float* a1s = (const float*)d_in[8];
    const float* a1d = (const float*)d_in[9];
    const float* b1  = (const float*)d_in[10];
    const float* W2  = (const float*)d_in[11];   // [1024,1024]
    const float* a2s = (const float*)d_in[12];
    const float* a2d = (const float*)d_in[13];
    const float* b2  = (const float*)d_in[14];
    const float* W3  = (const float*)d_in[15];   // [1024,2560]
    const float* a3s = (const float*)d_in[16];
    const float* a3d = (const float*)d_in[17];
    const float* b3  = (const float*)d_in[18];
    float* out = (float*)d_out;
    (void)ws_size; (void)in_sizes; (void)n_in; (void)out_size;

    char* W0 = (char*)d_ws;
    size_t off = 0;
    auto alloc = [&](size_t bytes) -> char* {
        char* p = W0 + off; off += (bytes + 255) & ~(size_t)255; return p;
    };
    u16* qe_c = (u16*)alloc(128ull * 2560 * 2);
    u16* of_c = (u16*)alloc(4608ull * 2048 * 2);
    const size_t szA = 4608ull * 2560 * 2;
    const size_t szB = 4608ull * 1024 * 2;
    const size_t szC = 4608ull * 1024 * 2;
    char* Abase = alloc(szA);
    char* Bbase = alloc(szB);
    char* Cbase = alloc(szC);
    float* alphaG = (float*)alloc(128ull * 5 * 36 * 36 * 4);   // 3.32 MB

    u16*   WqT   = (u16*)Abase;                           // [2048,2560]
    float* qpart = (float*)(Abase + 2048ull * 2560 * 2);
    u16*   x     = (u16*)Abase;
    u16*   g1    = (u16*)Abase;
    u16*   h3    = (u16*)Abase;
    u16*   WvT   = (u16*)Bbase;                           // [2048,2048]
    float* q     = (float*)(Bbase + 2048ull * 2048 * 2);
    u16*   W1T   = (u16*)Bbase;                           // [1024,2048]
    u16*   W2T   = (u16*)(Bbase + 1024ull * 2048 * 2);    // [1024,1024]
    u16*   g2    = (u16*)Bbase;
    u16*   h1    = (u16*)Cbase;
    u16*   h2    = (u16*)Cbase;
    u16*   W3T   = (u16*)Cbase;                           // [2560,1024]

    // S0: canonicalize activations to bf16 (qe K-padded to 2560)
    conv_all<<<dim3(9216 + 1280), 256, 0, stream>>>(of, of_c, qe, qe_c);

    // S1: transpose Wq (K-pad 2400->2560) + Wv in one launch
    transpose_cvt2<<<dim3(5120 + 4096), 256, 0, stream>>>(
        Wq, WqT, 2400, 2560, 2048, 5120,
        Wv, WvT, 2048, 2048, 2048);

    // S2-S3: q = qe @ Wq + bq   (splitK=5 x 512)
    gemm_tn<1><<<dim3(16, 1, 5), 256, 0, stream>>>(qe_c, WqT, 128, 2048, 2560, 512,
                                                   qpart, nullptr, nullptr, nullptr);
    qcombine<<<dim3(128 * 2048 / 256), 256, 0, stream>>>(qpart, bq, q, 128 * 2048, 5);

    // S4: x = (of @ Wv + bv) * q_rep
    gemm_tn<2><<<dim3(16, 36, 1), 256, 0, stream>>>(of_c, WvT, 4608, 2048, 2048, 2048,
                                                    nullptr, x, bv, q);

    // S5: transpose W1 + W2 in one launch
    transpose_cvt2<<<dim3(2048 + 1024), 256, 0, stream>>>(
        W1, W1T, 2048, 2048, 1024, 2048,
        W2, W2T, 1024, 1024, 1024);

    // S6-S7: layer 1 (fused attention)
    gemm_tn<0><<<dim3(8, 36, 1), 256, 0, stream>>>(x, W1T, 4608, 1024, 2048, 2048,
                                                   nullptr, h1, nullptr, nullptr);
    attn_kernel<4, 256, 1><<<dim3(4, B_IMG), 256, 0, stream>>>(h1, a1s, a1d, b1, nullptr, g1);

    // S8-S9: layer 2 (+ residual g1, fused attention)
    gemm_tn<0><<<dim3(8, 36, 1), 256, 0, stream>>>(g1, W2T, 4608, 1024, 1024, 1024,
                                                   nullptr, h2, nullptr, nullptr);
    attn_kernel<4, 256, 2><<<dim3(4, B_IMG), 256, 0, stream>>>(h2, a2s, a2d, b2, g1, g2);

    // S10-S13: layer 3 (5 heads, mean + b3) -> fp32 out
    transpose_cvt2<<<dim3(2560), 256, 0, stream>>>(
        W3, W3T, 1024, 1024, 2560, 2560,
        W3, W3T, 1024, 1024, 2560);
    gemm_tn<0><<<dim3(20, 36, 1), 256, 0, stream>>>(g2, W3T, 4608, 2560, 1024, 1024,
                                                    nullptr, h3, nullptr, nullptr);
    al_alpha<5, 512, true><<<dim3(5, B_IMG), 256, 0, stream>>>(h3, a3s, a3d, alphaG);
    attn_agg_mean<<<dim3(8, B_IMG), 192, 0, stream>>>(h3, alphaG, b3, out);
}